// Round 1
// 39918.738 us; speedup vs baseline: 1.4871x; 1.4871x over previous
//
#include <hip/hip_runtime.h>
#include <hip/hip_cooperative_groups.h>

namespace cg = cooperative_groups;

// R11: cooperative weight-stationary BiLSTM.
// 256 WGs x 512 thr (1/CU). WG = (dir, cs): 4 cells (16 gate rows), ALL 32 batches.
// Per step: gates[16][32] = Wslice[16x1024] @ [x_t | h][1024x32] with k split 32 ways,
// LDS partial reduction, pointwise, h published to d_ws double buffer, grid.sync.
// Weights: each WG re-reads only its 64KB slice per step -> L2-resident per XCD (2MB).

#define Bv 32
#define Tv 512
#define Dv 512
#define Hv 512

__device__ __forceinline__ float sigmf_(float x) { return 1.0f / (1.0f + __expf(-x)); }
__device__ __forceinline__ float tanhf_(float x) { return 2.0f / (1.0f + __expf(-2.0f * x)) - 1.0f; }

__global__ __launch_bounds__(512, 2) void bilstm_coop(
    const float* __restrict__ x, const int* __restrict__ lengths,
    const float* __restrict__ Wih_f, const float* __restrict__ Whh_f,
    const float* __restrict__ bih_f, const float* __restrict__ bhh_f,
    const float* __restrict__ Wih_b, const float* __restrict__ Whh_b,
    const float* __restrict__ bih_b, const float* __restrict__ bhh_b,
    float* __restrict__ out, float* __restrict__ hbuf)
{
    // xh[b][1032]: cols 0..511 = x_t, 512..1023 = h. Stride 1032 (x8 mod 32 banks, f4-aligned).
    // After GEMM the region is aliased as partial[512 rows][33].
    __shared__ float xh[Bv * 1032];          // 132,096 B
    __shared__ float gates[16 * 33];         // [row 16][b 32] pad 33
    __shared__ float cst[4 * Bv];
    __shared__ float bias_s[16];
    __shared__ int   len_s[Bv];

    const int tid = threadIdx.x;

    // XCD-aware decomposition: wg -> XCD is ~ (wg % 8); give each XCD one dir,
    // 32 contiguous cell-slices -> 2MB resident weight slice per XCD L2.
    const int w    = blockIdx.x;        // 0..255
    const int xcd  = w & 7;
    const int slot = w >> 3;            // 0..31
    const int lin  = xcd * 32 + slot;   // 0..255
    const int dir  = lin >> 7;          // 0/1
    const int cs   = lin & 127;         // 0..127
    const int c0   = cs * 4;

    const float* Wih = dir ? Wih_b : Wih_f;
    const float* Whh = dir ? Whh_b : Whh_f;
    const float* bih = dir ? bih_b : bih_f;
    const float* bhh = dir ? bhh_b : bhh_f;

    // ---- prologue ----
    if (tid < 16) {
        int g = tid >> 2, cj = tid & 3;
        int rg = g * Hv + c0 + cj;
        bias_s[tid] = bih[rg] + bhh[rg];
    }
    if (tid < Bv) len_s[tid] = lengths[tid];
    if (tid < 128) {
        int cj = tid >> 5, bl = tid & 31;
        cst[cj * Bv + bl] = 0.0f;
        // zero h buffer 0 (this WG's cells x all batches); union over WGs covers it all
        hbuf[((size_t)(0 * 2 + dir) * Bv + bl) * Hv + c0 + cj] = 0.0f;
    }
    __threadfence();
    cg::this_grid().sync();

    // thread tile: 4 rows (rpos==gate) x 8 batches (bpos) x k-seg of 32 (kseg)
    const int pos  = tid >> 5;      // 0..15
    const int kseg = tid & 31;      // 0..31
    const int rpos = pos >> 2;      // gate 0..3
    const int bpos = pos & 3;       // batch block of 8

    for (int s = 0; s < Tv; ++s) {
        const int t = dir ? (Tv - 1 - s) : s;
        const int p = s & 1;
        const float* hread = hbuf + (size_t)(p * 2 + dir) * (Bv * Hv);
        float*       hwrit = hbuf + (size_t)(((p ^ 1) * 2) + dir) * (Bv * Hv);

        // ---- stage [x_t | h] into LDS (8 + 8 float4 per thread) ----
        #pragma unroll
        for (int j = 0; j < 8; ++j) {
            int F  = tid + j * 512;           // 0..4095
            int bl = F >> 7, cf = F & 127;    // f4 index within 512 floats
            float4 v = *(const float4*)(x + ((size_t)bl * Tv + t) * Dv + cf * 4);
            *(float4*)(xh + bl * 1032 + cf * 4) = v;
        }
        #pragma unroll
        for (int j = 0; j < 8; ++j) {
            int F  = tid + j * 512;
            int bl = F >> 7, cf = F & 127;
            float4 v = *(const float4*)(hread + (size_t)bl * Hv + cf * 4);
            *(float4*)(xh + bl * 1032 + 512 + cf * 4) = v;
        }
        __syncthreads();

        // ---- GEMM: acc[4 rows][8 b] over this thread's 32 k's ----
        float acc[4][8];
        #pragma unroll
        for (int i = 0; i < 4; ++i)
            #pragma unroll
            for (int ib = 0; ib < 8; ++ib) acc[i][ib] = 0.0f;

        #pragma unroll
        for (int j = 0; j < 8; ++j) {
            const int kg  = j * 32 + kseg;    // f4 column 0..255
            const int col = kg * 4;           // float column 0..1023
            const float* Wb = (j < 4) ? Wih : Whh;
            const int  wcol = (j < 4) ? col : (col - 512);
            float4 wv[4];
            #pragma unroll
            for (int i = 0; i < 4; ++i)
                wv[i] = *(const float4*)(Wb + (size_t)(rpos * Hv + c0 + i) * Dv + wcol);
            float4 xv[8];
            #pragma unroll
            for (int ib = 0; ib < 8; ++ib)
                xv[ib] = *(const float4*)(xh + (bpos * 8 + ib) * 1032 + col);
            #pragma unroll
            for (int i = 0; i < 4; ++i)
                #pragma unroll
                for (int ib = 0; ib < 8; ++ib)
                    acc[i][ib] += wv[i].x * xv[ib].x + wv[i].y * xv[ib].y
                                + wv[i].z * xv[ib].z + wv[i].w * xv[ib].w;
        }
        __syncthreads();   // xh reads done; alias the region as partial[512][33]

        // ---- partial dump (stride-33 rows: 2-way max bank aliasing) ----
        float* part = xh;
        #pragma unroll
        for (int i = 0; i < 4; ++i)
            #pragma unroll
            for (int ib = 0; ib < 8; ++ib) {
                int row = (rpos * 4 + i) * 32 + (bpos * 8 + ib);
                part[row * 33 + kseg] = acc[i][ib];
            }
        __syncthreads();

        // ---- final reduce over 32 k-segments + bias -> gates ----
        {
            const float* pr = part + tid * 33;   // row == tid (0..511)
            float s0 = 0.f, s1 = 0.f, s2 = 0.f, s3 = 0.f;
            #pragma unroll
            for (int m = 0; m < 32; m += 4) {
                s0 += pr[m + 0]; s1 += pr[m + 1]; s2 += pr[m + 2]; s3 += pr[m + 3];
            }
            int lr = tid >> 5, bl = tid & 31;
            gates[lr * 33 + bl] = ((s0 + s1) + (s2 + s3)) + bias_s[lr];
        }
        __syncthreads();

        // ---- pointwise LSTM update, masked hold, publish ----
        if (tid < 128) {
            int cj = tid >> 5, bl = tid & 31;
            float gi = sigmf_(gates[(0 * 4 + cj) * 33 + bl]);
            float gf = sigmf_(gates[(1 * 4 + cj) * 33 + bl]);
            float gg = tanhf_(gates[(2 * 4 + cj) * 33 + bl]);
            float go = sigmf_(gates[(3 * 4 + cj) * 33 + bl]);
            float cold = cst[cj * Bv + bl];
            float cn = gf * cold + gi * gg;
            float hn = go * tanhf_(cn);
            bool  v  = (t < len_s[bl]);
            float hp = hread[(size_t)bl * Hv + c0 + cj];   // still in L2 from staging
            float ho = v ? hn : hp;
            cst[cj * Bv + bl] = v ? cn : cold;
            hwrit[(size_t)bl * Hv + c0 + cj] = ho;
            out[((size_t)bl * Tv + t) * (2 * Hv) + dir * Hv + c0 + cj] = ho;
        }
        __threadfence();          // wb+inv (agent): publish h, drop stale L2 copies
        cg::this_grid().sync();
    }
}

// ---------------- fallback: R10 kernel (unchanged) ----------------
__global__ __launch_bounds__(1024, 1) void bilstm_simple(
    const float* __restrict__ x,
    const int* __restrict__ lengths,
    const float* __restrict__ Wih_f, const float* __restrict__ Whh_f,
    const float* __restrict__ bih_f, const float* __restrict__ bhh_f,
    const float* __restrict__ Wih_b, const float* __restrict__ Whh_b,
    const float* __restrict__ bih_b, const float* __restrict__ bhh_b,
    float* __restrict__ out)
{
    __shared__ float xh[Dv + Hv];
    __shared__ float cst[Hv];
    __shared__ float gates[4 * Hv];
    __shared__ float bias[4 * Hv];

    const int tid  = threadIdx.x;
    const int wave = tid >> 6;
    const int lane = tid & 63;
    const int dir  = blockIdx.x >> 5;
    const int b    = blockIdx.x & 31;

    const float* Wih = dir ? Wih_b : Wih_f;
    const float* Whh = dir ? Whh_b : Whh_f;
    const float* bih = dir ? bih_b : bih_f;
    const float* bhh = dir ? bhh_b : bhh_f;

    for (int i = tid; i < 4 * Hv; i += 1024) bias[i] = bih[i] + bhh[i];
    for (int i = tid; i < Hv; i += 1024) { xh[Dv + i] = 0.f; cst[i] = 0.f; }
    const int len = lengths[b];

    const float* Wbase = (lane < 32) ? Wih : Whh;
    const int koff = (lane & 31) * 16;

    for (int s = 0; s < Tv; ++s) {
        const int t = dir ? (Tv - 1 - s) : s;
        __syncthreads();
        for (int i = tid; i < Dv; i += 1024)
            xh[i] = x[((size_t)b * Tv + t) * Dv + i];
        __syncthreads();

        float4 xr0 = *(const float4*)(xh + lane * 16 + 0);
        float4 xr1 = *(const float4*)(xh + lane * 16 + 4);
        float4 xr2 = *(const float4*)(xh + lane * 16 + 8);
        float4 xr3 = *(const float4*)(xh + lane * 16 + 12);

        #pragma unroll 4
        for (int rr = 0; rr < 128; ++rr) {
            const int row = wave * 128 + rr;
            const float4* wr = (const float4*)(Wbase + (size_t)row * 512 + koff);
            const float4 w0 = wr[0], w1 = wr[1], w2 = wr[2], w3 = wr[3];
            float acc = w0.x * xr0.x + w0.y * xr0.y + w0.z * xr0.z + w0.w * xr0.w
                      + w1.x * xr1.x + w1.y * xr1.y + w1.z * xr1.z + w1.w * xr1.w
                      + w2.x * xr2.x + w2.y * xr2.y + w2.z * xr2.z + w2.w * xr2.w
                      + w3.x * xr3.x + w3.y * xr3.y + w3.z * xr3.z + w3.w * xr3.w;
            #pragma unroll
            for (int off = 32; off > 0; off >>= 1)
                acc += __shfl_xor(acc, off, 64);
            if (lane == 0) gates[row] = acc;
        }
        __syncthreads();

        if (tid < Hv) {
            const int cc = tid;
            const float gi = sigmf_(gates[0 * Hv + cc] + bias[0 * Hv + cc]);
            const float gf = sigmf_(gates[1 * Hv + cc] + bias[1 * Hv + cc]);
            const float gg = tanhf_(gates[2 * Hv + cc] + bias[2 * Hv + cc]);
            const float go = sigmf_(gates[3 * Hv + cc] + bias[3 * Hv + cc]);
            const float cn = gf * cst[cc] + gi * gg;
            const float hn = go * tanhf_(cn);
            const bool v = (t < len);
            const float hnew = v ? hn : xh[Dv + cc];
            cst[cc] = v ? cn : cst[cc];
            xh[Dv + cc] = hnew;
            out[((size_t)b * Tv + t) * (2 * Hv) + dir * Hv + cc] = hnew;
        }
    }
}

extern "C" void kernel_launch(void* const* d_in, const int* in_sizes, int n_in,
                              void* d_out, int out_size, void* d_ws, size_t ws_size,
                              hipStream_t stream) {
    (void)out_size;

    const void *xv, *len_p, *Wihf, *Whhf, *bihf, *bhhf, *Wihb, *Whhb, *bihb, *bhhb;
    if (n_in == 10 && in_sizes[9] == 8388608 && in_sizes[8] == 32) {
        // alphabetical pytree order fallback
        Whhb = d_in[0]; Whhf = d_in[1]; Wihb = d_in[2]; Wihf = d_in[3];
        bhhb = d_in[4]; bhhf = d_in[5]; bihb = d_in[6]; bihf = d_in[7];
        len_p = d_in[8]; xv = d_in[9];
    } else {
        // documented dict order
        xv = d_in[0]; len_p = d_in[1];
        Wihf = d_in[2]; Whhf = d_in[3]; bihf = d_in[4]; bhhf = d_in[5];
        Wihb = d_in[6]; Whhb = d_in[7]; bihb = d_in[8]; bhhb = d_in[9];
    }

    const float* xf  = (const float*)xv;
    const int*   lp  = (const int*)len_p;
    const float* wif = (const float*)Wihf;  const float* whf = (const float*)Whhf;
    const float* bif = (const float*)bihf;  const float* bhf = (const float*)bhhf;
    const float* wib = (const float*)Wihb;  const float* whb = (const float*)Whhb;
    const float* bib = (const float*)bihb;  const float* bhb = (const float*)bhhb;
    float* outp = (float*)d_out;
    float* hb   = (float*)d_ws;

    const size_t need_ws = (size_t)2 * 2 * Bv * Hv * sizeof(float);  // 256 KB
    if (ws_size >= need_ws) {
        void* args[12] = { &xf, &lp, &wif, &whf, &bif, &bhf,
                           &wib, &whb, &bib, &bhb, &outp, &hb };
        hipError_t e = hipLaunchCooperativeKernel((const void*)bilstm_coop,
                                                  dim3(256), dim3(512),
                                                  args, 0, stream);
        if (e == hipSuccess) return;
    }

    // fallback: R10 kernel (correct, slow)
    bilstm_simple<<<dim3(64), dim3(1024), 0, stream>>>(
        xf, lp, wif, whf, bif, bhf, wib, whb, bib, bhb, outp);
}

// Round 2
// 14737.061 us; speedup vs baseline: 4.0282x; 2.7087x over previous
//
#include <hip/hip_runtime.h>
#include <hip/hip_cooperative_groups.h>

namespace cg = cooperative_groups;

// R12: cooperative weight-stationary BiLSTM with CUSTOM split-phase barrier.
// 256 WGs x 512 thr (1 per CU). WG = (dir, cell-slice): 4 cells x 16 gate rows,
// all 32 batches. Per-dir barrier (128 WGs) striped over 4 lines in d_ws;
// arrive-early/wait-late: x-part GEMM runs before the wait, only h-part GEMM +
// pointwise + publish are on the recurrence critical path. h is exchanged
// through `out` itself (out[b][t][dir*H + c] == h_t, holds included).

#define Bv 32
#define Tv 512
#define Dv 512
#define Hv 512
#define XS 520            // x LDS row stride (floats): 8 mod 128 -> conflict-free
#define HS 520            // h LDS row stride
#define PUN 16896         // union size: max(32*HS=16640, 512*33=16896)

__device__ __forceinline__ float sigmf_(float x) { return 1.0f / (1.0f + __expf(-x)); }
__device__ __forceinline__ float tanhf_(float x) { return 2.0f / (1.0f + __expf(-2.0f * x)) - 1.0f; }

__global__ __launch_bounds__(512, 2) void bilstm_coop2(
    const float* __restrict__ x, const int* __restrict__ lengths,
    const float* __restrict__ Wih_f, const float* __restrict__ Whh_f,
    const float* __restrict__ bih_f, const float* __restrict__ bhh_f,
    const float* __restrict__ Wih_b, const float* __restrict__ Whh_b,
    const float* __restrict__ bih_b, const float* __restrict__ bhh_b,
    float* __restrict__ out, unsigned int* __restrict__ cnt)   // cnt: 8 lines x 64 uints
{
    __shared__ float xb[Bv * XS];      // x_t stage              (66,560 B)
    __shared__ float hu[PUN];          // h stage / partial union (67,584 B)
    __shared__ float gates[16 * 33];
    __shared__ float cst[4 * Bv];
    __shared__ float bias_s[16];
    __shared__ int   len_s[Bv];

    const int tid = threadIdx.x;
    const int w   = blockIdx.x;

    // blockIdx -> XCD is (w & 7). XCDs 0..3 = dir 0, 4..7 = dir 1.
    const int xcd  = w & 7;
    const int dir  = xcd >> 2;
    const int slot = w >> 3;                    // 0..31
    const int cs   = (xcd & 3) * 32 + slot;     // 0..127 cell-slice within dir
    const int c0   = cs * 4;
    const int line = slot & 3;                  // 4 barrier lines per dir, 32 WG each

    unsigned int* mycnt = cnt + (dir * 4 + line) * 64;   // 256B-strided lines
    unsigned int* dcnt  = cnt + dir * 4 * 64;

    const float* Wih = dir ? Wih_b : Wih_f;
    const float* Whh = dir ? Whh_b : Whh_f;
    const float* bih = dir ? bih_b : bih_f;
    const float* bhh = dir ? bhh_b : bhh_f;

    // ---- prologue ----
    if (w == 0 && tid == 0) {
        #pragma unroll
        for (int l = 0; l < 8; ++l) cnt[l * 64] = 0u;
        __threadfence();
    }
    if (tid < 16) {
        int g = tid >> 2, cj = tid & 3;
        int rg = g * Hv + c0 + cj;
        bias_s[tid] = bih[rg] + bhh[rg];
    }
    if (tid < Bv) len_s[tid] = lengths[tid];
    if (tid < 128) cst[tid] = 0.0f;
    cg::this_grid().sync();   // once per launch: counters zeroed + visible

    // thread tile: 4 gate-rows (rpos) x 8 batches (bpos) x 32-float k-segment
    const int pos  = tid >> 5;      // 0..15
    const int kseg = tid & 31;      // 0..31
    const int rpos = pos >> 2;      // gate 0..3
    const int bpos = pos & 3;       // batch block of 8

    for (int s = 0; s < Tv; ++s) {
        const int t = dir ? (Tv - 1 - s) : s;

        // ---- 1. stage x_t (independent of recurrence) ----
        #pragma unroll
        for (int j = 0; j < 8; ++j) {
            int F  = tid + j * 512;            // 0..4095 f4-slots
            int bl = F >> 7, cf = F & 127;
            *(float4*)(xb + bl * XS + cf * 4) =
                *(const float4*)(x + ((size_t)bl * Tv + t) * Dv + cf * 4);
        }
        __syncthreads();

        // ---- 2. x-part GEMM: acc[4][8] over this thread's 32 k's (Wih) ----
        float acc[4][8];
        #pragma unroll
        for (int i = 0; i < 4; ++i)
            #pragma unroll
            for (int ib = 0; ib < 8; ++ib) acc[i][ib] = 0.0f;

        #pragma unroll
        for (int j = 0; j < 4; ++j) {
            const int col = (j * 32 + kseg) * 4;    // float col 0..511
            float4 wv[4];
            #pragma unroll
            for (int i = 0; i < 4; ++i)
                wv[i] = *(const float4*)(Wih + (size_t)(rpos * Hv + c0 + i) * Dv + col);
            float4 xv[8];
            #pragma unroll
            for (int ib = 0; ib < 8; ++ib)
                xv[ib] = *(const float4*)(xb + (bpos * 8 + ib) * XS + col);
            #pragma unroll
            for (int i = 0; i < 4; ++i)
                #pragma unroll
                for (int ib = 0; ib < 8; ++ib)
                    acc[i][ib] += wv[i].x * xv[ib].x + wv[i].y * xv[ib].y
                                + wv[i].z * xv[ib].z + wv[i].w * xv[ib].w;
        }

        // ---- 3. WAIT for h_{s-1} published (leader spins, 4 lines) ----
        if (tid == 0 && s > 0) {
            const unsigned int tgt = 32u * (unsigned int)s;
            #pragma unroll
            for (int l = 0; l < 4; ++l) {
                while (__hip_atomic_load(&dcnt[l * 64], __ATOMIC_RELAXED,
                                         __HIP_MEMORY_SCOPE_AGENT) < tgt)
                    __builtin_amdgcn_s_sleep(2);
            }
            __threadfence();   // acquire: invalidate stale L1/L2 before h loads
        }
        __syncthreads();

        // ---- 4. stage h_{s-1} from out (or zeros at s==0) ----
        if (s == 0) {
            #pragma unroll
            for (int j = 0; j < 8; ++j) {
                int F  = tid + j * 512;
                int bl = F >> 7, cf = F & 127;
                *(float4*)(hu + bl * HS + cf * 4) = make_float4(0.f, 0.f, 0.f, 0.f);
            }
        } else {
            const int tp = dir ? (t + 1) : (t - 1);
            #pragma unroll
            for (int j = 0; j < 8; ++j) {
                int F  = tid + j * 512;
                int bl = F >> 7, cf = F & 127;
                *(float4*)(hu + bl * HS + cf * 4) =
                    *(const float4*)(out + ((size_t)bl * Tv + tp) * (2 * Hv)
                                         + dir * Hv + cf * 4);
            }
        }
        __syncthreads();

        // hold-value for masked batches: read before hu is reused as partial
        float hpv = 0.0f;
        if (tid < 128) hpv = hu[(tid & 31) * HS + c0 + (tid >> 5)];

        // ---- 5. h-part GEMM accumulate (Whh) ----
        #pragma unroll
        for (int j = 0; j < 4; ++j) {
            const int col = (j * 32 + kseg) * 4;
            float4 wv[4];
            #pragma unroll
            for (int i = 0; i < 4; ++i)
                wv[i] = *(const float4*)(Whh + (size_t)(rpos * Hv + c0 + i) * Dv + col);
            float4 hv[8];
            #pragma unroll
            for (int ib = 0; ib < 8; ++ib)
                hv[ib] = *(const float4*)(hu + (bpos * 8 + ib) * HS + col);
            #pragma unroll
            for (int i = 0; i < 4; ++i)
                #pragma unroll
                for (int ib = 0; ib < 8; ++ib)
                    acc[i][ib] += wv[i].x * hv[ib].x + wv[i].y * hv[ib].y
                                + wv[i].z * hv[ib].z + wv[i].w * hv[ib].w;
        }
        __syncthreads();   // hu reads done; alias as partial[512][33]

        // ---- 6. partial dump ----
        float* part = hu;
        #pragma unroll
        for (int i = 0; i < 4; ++i)
            #pragma unroll
            for (int ib = 0; ib < 8; ++ib) {
                int row = (rpos * 4 + i) * 32 + (bpos * 8 + ib);
                part[row * 33 + kseg] = acc[i][ib];
            }
        __syncthreads();

        // ---- 7. final reduce + bias -> gates ----
        {
            const float* pr = part + tid * 33;
            float s0 = 0.f, s1 = 0.f, s2 = 0.f, s3 = 0.f;
            #pragma unroll
            for (int m = 0; m < 32; m += 4) {
                s0 += pr[m + 0]; s1 += pr[m + 1]; s2 += pr[m + 2]; s3 += pr[m + 3];
            }
            int lr = tid >> 5, bl = tid & 31;
            gates[lr * 33 + bl] = ((s0 + s1) + (s2 + s3)) + bias_s[lr];
        }
        __syncthreads();

        // ---- 8. pointwise LSTM update, masked hold, publish to out ----
        if (tid < 128) {
            int cj = tid >> 5, bl = tid & 31;
            float gi = sigmf_(gates[(0 * 4 + cj) * 33 + bl]);
            float gf = sigmf_(gates[(1 * 4 + cj) * 33 + bl]);
            float gg = tanhf_(gates[(2 * 4 + cj) * 33 + bl]);
            float go = sigmf_(gates[(3 * 4 + cj) * 33 + bl]);
            float cold = cst[cj * Bv + bl];
            float cn = gf * cold + gi * gg;
            float hn = go * tanhf_(cn);
            bool  v  = (t < len_s[bl]);
            float ho = v ? hn : hpv;
            cst[cj * Bv + bl] = v ? cn : cold;
            out[((size_t)bl * Tv + t) * (2 * Hv) + dir * Hv + c0 + cj] = ho;
        }
        __syncthreads();   // publishes issued & drained (syncthreads waits vmcnt)

        // ---- 9. ARRIVE (release) ----
        if (tid == 0) {
            __threadfence();   // write back this XCD's L2 so h is LLC-visible
            __hip_atomic_fetch_add(mycnt, 1u, __ATOMIC_RELAXED,
                                   __HIP_MEMORY_SCOPE_AGENT);
        }
    }
}

// ---------------- fallback: R10 kernel (unchanged, correct, slow) ----------------
__global__ __launch_bounds__(1024, 1) void bilstm_simple(
    const float* __restrict__ x,
    const int* __restrict__ lengths,
    const float* __restrict__ Wih_f, const float* __restrict__ Whh_f,
    const float* __restrict__ bih_f, const float* __restrict__ bhh_f,
    const float* __restrict__ Wih_b, const float* __restrict__ Whh_b,
    const float* __restrict__ bih_b, const float* __restrict__ bhh_b,
    float* __restrict__ out)
{
    __shared__ float xh[Dv + Hv];
    __shared__ float cst[Hv];
    __shared__ float gates[4 * Hv];
    __shared__ float bias[4 * Hv];

    const int tid  = threadIdx.x;
    const int wave = tid >> 6;
    const int lane = tid & 63;
    const int dir  = blockIdx.x >> 5;
    const int b    = blockIdx.x & 31;

    const float* Wih = dir ? Wih_b : Wih_f;
    const float* Whh = dir ? Whh_b : Whh_f;
    const float* bih = dir ? bih_b : bih_f;
    const float* bhh = dir ? bhh_b : bhh_f;

    for (int i = tid; i < 4 * Hv; i += 1024) bias[i] = bih[i] + bhh[i];
    for (int i = tid; i < Hv; i += 1024) { xh[Dv + i] = 0.f; cst[i] = 0.f; }
    const int len = lengths[b];

    const float* Wbase = (lane < 32) ? Wih : Whh;
    const int koff = (lane & 31) * 16;

    for (int s = 0; s < Tv; ++s) {
        const int t = dir ? (Tv - 1 - s) : s;
        __syncthreads();
        for (int i = tid; i < Dv; i += 1024)
            xh[i] = x[((size_t)b * Tv + t) * Dv + i];
        __syncthreads();

        float4 xr0 = *(const float4*)(xh + lane * 16 + 0);
        float4 xr1 = *(const float4*)(xh + lane * 16 + 4);
        float4 xr2 = *(const float4*)(xh + lane * 16 + 8);
        float4 xr3 = *(const float4*)(xh + lane * 16 + 12);

        #pragma unroll 4
        for (int rr = 0; rr < 128; ++rr) {
            const int row = wave * 128 + rr;
            const float4* wr = (const float4*)(Wbase + (size_t)row * 512 + koff);
            const float4 w0 = wr[0], w1 = wr[1], w2 = wr[2], w3 = wr[3];
            float acc = w0.x * xr0.x + w0.y * xr0.y + w0.z * xr0.z + w0.w * xr0.w
                      + w1.x * xr1.x + w1.y * xr1.y + w1.z * xr1.z + w1.w * xr1.w
                      + w2.x * xr2.x + w2.y * xr2.y + w2.z * xr2.z + w2.w * xr2.w
                      + w3.x * xr3.x + w3.y * xr3.y + w3.z * xr3.z + w3.w * xr3.w;
            #pragma unroll
            for (int off = 32; off > 0; off >>= 1)
                acc += __shfl_xor(acc, off, 64);
            if (lane == 0) gates[row] = acc;
        }
        __syncthreads();

        if (tid < Hv) {
            const int cc = tid;
            const float gi = sigmf_(gates[0 * Hv + cc] + bias[0 * Hv + cc]);
            const float gf = sigmf_(gates[1 * Hv + cc] + bias[1 * Hv + cc]);
            const float gg = tanhf_(gates[2 * Hv + cc] + bias[2 * Hv + cc]);
            const float go = sigmf_(gates[3 * Hv + cc] + bias[3 * Hv + cc]);
            const float cn = gf * cst[cc] + gi * gg;
            const float hn = go * tanhf_(cn);
            const bool v = (t < len);
            const float hnew = v ? hn : xh[Dv + cc];
            cst[cc] = v ? cn : cst[cc];
            xh[Dv + cc] = hnew;
            out[((size_t)b * Tv + t) * (2 * Hv) + dir * Hv + cc] = hnew;
        }
    }
}

extern "C" void kernel_launch(void* const* d_in, const int* in_sizes, int n_in,
                              void* d_out, int out_size, void* d_ws, size_t ws_size,
                              hipStream_t stream) {
    (void)out_size;

    const void *xv, *len_p, *Wihf, *Whhf, *bihf, *bhhf, *Wihb, *Whhb, *bihb, *bhhb;
    if (n_in == 10 && in_sizes[9] == 8388608 && in_sizes[8] == 32) {
        // alphabetical pytree order fallback
        Whhb = d_in[0]; Whhf = d_in[1]; Wihb = d_in[2]; Wihf = d_in[3];
        bhhb = d_in[4]; bhhf = d_in[5]; bihb = d_in[6]; bihf = d_in[7];
        len_p = d_in[8]; xv = d_in[9];
    } else {
        // documented dict order
        xv = d_in[0]; len_p = d_in[1];
        Wihf = d_in[2]; Whhf = d_in[3]; bihf = d_in[4]; bhhf = d_in[5];
        Wihb = d_in[6]; Whhb = d_in[7]; bihb = d_in[8]; bhhb = d_in[9];
    }

    const float* xf  = (const float*)xv;
    const int*   lp  = (const int*)len_p;
    const float* wif = (const float*)Wihf;  const float* whf = (const float*)Whhf;
    const float* bif = (const float*)bihf;  const float* bhf = (const float*)bhhf;
    const float* wib = (const float*)Wihb;  const float* whb = (const float*)Whhb;
    const float* bib = (const float*)bihb;  const float* bhb = (const float*)bhhb;
    float* outp = (float*)d_out;
    unsigned int* cntp = (unsigned int*)d_ws;

    if (ws_size >= 2048) {
        void* args[12] = { &xf, &lp, &wif, &whf, &bif, &bhf,
                           &wib, &whb, &bib, &bhb, &outp, &cntp };
        hipError_t e = hipLaunchCooperativeKernel((const void*)bilstm_coop2,
                                                  dim3(256), dim3(512),
                                                  args, 0, stream);
        if (e == hipSuccess) return;
    }

    // fallback: R10 kernel
    bilstm_simple<<<dim3(64), dim3(1024), 0, stream>>>(
        xf, lp, wif, whf, bif, bhf, wib, whb, bib, bhb, outp);
}

// Round 3
// 9953.199 us; speedup vs baseline: 5.9643x; 1.4806x over previous
//
#include <hip/hip_runtime.h>
#include <hip/hip_cooperative_groups.h>

namespace cg = cooperative_groups;

// R13: cooperative weight-stationary BiLSTM, NO cache-wide fences.
// 256 WGs x 512 thr (1/CU). WG = (dir, cell-slice): 4 cells x 16 gate rows,
// all 32 batches. Custom split-phase barrier (4 lines/dir in d_ws).
// h exchange: writers publish via agent-scope (sc1 write-through) stores into
// out[t] (fresh address every step); readers use NORMAL cached loads -> each
// XCD L2 misses once per line, serves its 32 WGs, never sees a stale copy.
// No __threadfence in the loop => weights/x stay L2-resident. Whh slice is
// hoisted to registers (step-invariant) so the post-wait GEMM is LDS+FMA only.

#define Bv 32
#define Tv 512
#define Dv 512
#define Hv 512
#define XS 520            // x LDS row stride (floats), conflict-benign
#define HS 520            // h LDS row stride
#define PUN 16896         // union: max(32*HS=16640, 512*33=16896)

__device__ __forceinline__ float sigmf_(float x) { return 1.0f / (1.0f + __expf(-x)); }
__device__ __forceinline__ float tanhf_(float x) { return 2.0f / (1.0f + __expf(-2.0f * x)) - 1.0f; }

__global__ __launch_bounds__(512, 2) void bilstm_coop3(
    const float* __restrict__ x, const int* __restrict__ lengths,
    const float* __restrict__ Wih_f, const float* __restrict__ Whh_f,
    const float* __restrict__ bih_f, const float* __restrict__ bhh_f,
    const float* __restrict__ Wih_b, const float* __restrict__ Whh_b,
    const float* __restrict__ bih_b, const float* __restrict__ bhh_b,
    float* __restrict__ out, unsigned int* __restrict__ cnt)   // cnt: 8 lines x 64 uints
{
    __shared__ float xb[Bv * XS];      // x_t stage
    __shared__ float hu[PUN];          // h stage / partial union
    __shared__ float gates[16 * 33];
    __shared__ float cst[4 * Bv];
    __shared__ float bias_s[16];
    __shared__ int   len_s[Bv];

    const int tid = threadIdx.x;
    const int w   = blockIdx.x;

    // blockIdx -> XCD is (w & 7). XCDs 0..3 = dir 0, XCDs 4..7 = dir 1.
    const int xcd  = w & 7;
    const int dir  = xcd >> 2;
    const int slot = w >> 3;                    // 0..31
    const int cs   = (xcd & 3) * 32 + slot;     // 0..127 cell-slice within dir
    const int c0   = cs * 4;
    const int line = slot & 3;                  // 4 barrier lines/dir, 32 WG each

    unsigned int* mycnt = cnt + (dir * 4 + line) * 64;   // 256B-strided lines

    const float* Wih = dir ? Wih_b : Wih_f;
    const float* Whh = dir ? Whh_b : Whh_f;
    const float* bih = dir ? bih_b : bih_f;
    const float* bhh = dir ? bhh_b : bhh_f;

    // ---- prologue ----
    if (w == 0 && tid == 0) {
        #pragma unroll
        for (int l = 0; l < 8; ++l) cnt[l * 64] = 0u;
        __threadfence();
    }
    if (tid < 16) {
        int g = tid >> 2, cj = tid & 3;
        int rg = g * Hv + c0 + cj;
        bias_s[tid] = bih[rg] + bhh[rg];
    }
    if (tid < Bv) len_s[tid] = lengths[tid];
    if (tid < 128) cst[tid] = 0.0f;
    cg::this_grid().sync();   // once per launch: counters zeroed + visible

    // thread tile: 4 gate-rows (rpos) x 8 batches (bpos) x 32-float k-segment
    const int pos  = tid >> 5;      // 0..15
    const int kseg = tid & 31;      // 0..31
    const int rpos = pos >> 2;      // gate 0..3
    const int bpos = pos & 3;       // batch block of 8

    // ---- hoist step-invariant Whh slice into registers (16 x float4) ----
    float4 whr[4][4];
    #pragma unroll
    for (int j = 0; j < 4; ++j)
        #pragma unroll
        for (int i = 0; i < 4; ++i)
            whr[j][i] = *(const float4*)(Whh + (size_t)(rpos * Hv + c0 + i) * Dv
                                             + (j * 32 + kseg) * 4);

    for (int s = 0; s < Tv; ++s) {
        const int t = dir ? (Tv - 1 - s) : s;

        // ---- 1. stage x_t (normal cached loads; L2-shared per XCD) ----
        #pragma unroll
        for (int j = 0; j < 8; ++j) {
            int F  = tid + j * 512;
            int bl = F >> 7, cf = F & 127;
            *(float4*)(xb + bl * XS + cf * 4) =
                *(const float4*)(x + ((size_t)bl * Tv + t) * Dv + cf * 4);
        }
        __syncthreads();

        // ---- 2. x-part GEMM (Wih from L2-resident lines) ----
        float acc[4][8];
        #pragma unroll
        for (int i = 0; i < 4; ++i)
            #pragma unroll
            for (int ib = 0; ib < 8; ++ib) acc[i][ib] = 0.0f;

        #pragma unroll
        for (int j = 0; j < 4; ++j) {
            const int col = (j * 32 + kseg) * 4;
            float4 wv[4];
            #pragma unroll
            for (int i = 0; i < 4; ++i)
                wv[i] = *(const float4*)(Wih + (size_t)(rpos * Hv + c0 + i) * Dv + col);
            float4 xv[8];
            #pragma unroll
            for (int ib = 0; ib < 8; ++ib)
                xv[ib] = *(const float4*)(xb + (bpos * 8 + ib) * XS + col);
            #pragma unroll
            for (int i = 0; i < 4; ++i)
                #pragma unroll
                for (int ib = 0; ib < 8; ++ib)
                    acc[i][ib] += wv[i].x * xv[ib].x + wv[i].y * xv[ib].y
                                + wv[i].z * xv[ib].z + wv[i].w * xv[ib].w;
        }

        // ---- 3. WAIT for h_{s-1}: 4 parallel pollers, relaxed, NO fence ----
        if (s > 0 && tid < 4) {
            const unsigned int tgt = 32u * (unsigned int)s;
            const unsigned int* dl = cnt + (dir * 4 + tid) * 64;
            while (__hip_atomic_load(dl, __ATOMIC_RELAXED,
                                     __HIP_MEMORY_SCOPE_AGENT) < tgt)
                __builtin_amdgcn_s_sleep(1);
        }
        __syncthreads();   // compiler + wave barrier: staging can't hoist above

        // ---- 4. stage h_{s-1} from out via NORMAL cached loads ----
        // Safe: address t' is fresh to this XCD's L2 (writers used sc1
        // write-through, readers touch each t' exactly once) -> miss -> LLC.
        if (s == 0) {
            #pragma unroll
            for (int j = 0; j < 8; ++j) {
                int F  = tid + j * 512;
                int bl = F >> 7, cf = F & 127;
                *(float4*)(hu + bl * HS + cf * 4) = make_float4(0.f, 0.f, 0.f, 0.f);
            }
        } else {
            const int tp = dir ? (t + 1) : (t - 1);
            #pragma unroll
            for (int j = 0; j < 8; ++j) {
                int F  = tid + j * 512;
                int bl = F >> 7, cf = F & 127;
                *(float4*)(hu + bl * HS + cf * 4) =
                    *(const float4*)(out + ((size_t)bl * Tv + tp) * (2 * Hv)
                                         + dir * Hv + cf * 4);
            }
        }
        __syncthreads();

        // hold-value for masked batches (read before hu is reused as partial)
        float hpv = 0.0f;
        if (tid < 128) hpv = hu[(tid & 31) * HS + c0 + (tid >> 5)];

        // ---- 5. h-part GEMM: pure LDS + register weights ----
        #pragma unroll
        for (int j = 0; j < 4; ++j) {
            const int col = (j * 32 + kseg) * 4;
            float4 hv[8];
            #pragma unroll
            for (int ib = 0; ib < 8; ++ib)
                hv[ib] = *(const float4*)(hu + (bpos * 8 + ib) * HS + col);
            #pragma unroll
            for (int i = 0; i < 4; ++i)
                #pragma unroll
                for (int ib = 0; ib < 8; ++ib)
                    acc[i][ib] += whr[j][i].x * hv[ib].x + whr[j][i].y * hv[ib].y
                                + whr[j][i].z * hv[ib].z + whr[j][i].w * hv[ib].w;
        }
        __syncthreads();   // hu reads done; alias as partial[512][33]

        // ---- 6. partial dump ----
        float* part = hu;
        #pragma unroll
        for (int i = 0; i < 4; ++i)
            #pragma unroll
            for (int ib = 0; ib < 8; ++ib) {
                int row = (rpos * 4 + i) * 32 + (bpos * 8 + ib);
                part[row * 33 + kseg] = acc[i][ib];
            }
        __syncthreads();

        // ---- 7. final reduce + bias -> gates ----
        {
            const float* pr = part + tid * 33;
            float s0 = 0.f, s1 = 0.f, s2 = 0.f, s3 = 0.f;
            #pragma unroll
            for (int m = 0; m < 32; m += 4) {
                s0 += pr[m + 0]; s1 += pr[m + 1]; s2 += pr[m + 2]; s3 += pr[m + 3];
            }
            int lr = tid >> 5, bl = tid & 31;
            gates[lr * 33 + bl] = ((s0 + s1) + (s2 + s3)) + bias_s[lr];
        }
        __syncthreads();

        // ---- 8. pointwise update + publish via agent-scope write-through ----
        if (tid < 128) {
            int cj = tid >> 5, bl = tid & 31;
            float gi = sigmf_(gates[(0 * 4 + cj) * 33 + bl]);
            float gf = sigmf_(gates[(1 * 4 + cj) * 33 + bl]);
            float gg = tanhf_(gates[(2 * 4 + cj) * 33 + bl]);
            float go = sigmf_(gates[(3 * 4 + cj) * 33 + bl]);
            float cold = cst[cj * Bv + bl];
            float cn = gf * cold + gi * gg;
            float hn = go * tanhf_(cn);
            bool  v  = (t < len_s[bl]);
            float ho = v ? hn : hpv;
            cst[cj * Bv + bl] = v ? cn : cold;
            __hip_atomic_store(out + ((size_t)bl * Tv + t) * (2 * Hv)
                                   + dir * Hv + c0 + cj,
                               ho, __ATOMIC_RELAXED, __HIP_MEMORY_SCOPE_AGENT);
        }
        __syncthreads();   // all waves drain vmcnt before the arrive

        // ---- 9. ARRIVE (release; dirty set is empty -> cheap) ----
        if (tid == 0)
            __hip_atomic_fetch_add(mycnt, 1u, __ATOMIC_RELEASE,
                                   __HIP_MEMORY_SCOPE_AGENT);
    }
}

// ---------------- fallback: R10 kernel (unchanged, correct, slow) ----------------
__global__ __launch_bounds__(1024, 1) void bilstm_simple(
    const float* __restrict__ x,
    const int* __restrict__ lengths,
    const float* __restrict__ Wih_f, const float* __restrict__ Whh_f,
    const float* __restrict__ bih_f, const float* __restrict__ bhh_f,
    const float* __restrict__ Wih_b, const float* __restrict__ Whh_b,
    const float* __restrict__ bih_b, const float* __restrict__ bhh_b,
    float* __restrict__ out)
{
    __shared__ float xh[Dv + Hv];
    __shared__ float cst[Hv];
    __shared__ float gates[4 * Hv];
    __shared__ float bias[4 * Hv];

    const int tid  = threadIdx.x;
    const int wave = tid >> 6;
    const int lane = tid & 63;
    const int dir  = blockIdx.x >> 5;
    const int b    = blockIdx.x & 31;

    const float* Wih = dir ? Wih_b : Wih_f;
    const float* Whh = dir ? Whh_b : Whh_f;
    const float* bih = dir ? bih_b : bih_f;
    const float* bhh = dir ? bhh_b : bhh_f;

    for (int i = tid; i < 4 * Hv; i += 1024) bias[i] = bih[i] + bhh[i];
    for (int i = tid; i < Hv; i += 1024) { xh[Dv + i] = 0.f; cst[i] = 0.f; }
    const int len = lengths[b];

    const float* Wbase = (lane < 32) ? Wih : Whh;
    const int koff = (lane & 31) * 16;

    for (int s = 0; s < Tv; ++s) {
        const int t = dir ? (Tv - 1 - s) : s;
        __syncthreads();
        for (int i = tid; i < Dv; i += 1024)
            xh[i] = x[((size_t)b * Tv + t) * Dv + i];
        __syncthreads();

        float4 xr0 = *(const float4*)(xh + lane * 16 + 0);
        float4 xr1 = *(const float4*)(xh + lane * 16 + 4);
        float4 xr2 = *(const float4*)(xh + lane * 16 + 8);
        float4 xr3 = *(const float4*)(xh + lane * 16 + 12);

        #pragma unroll 4
        for (int rr = 0; rr < 128; ++rr) {
            const int row = wave * 128 + rr;
            const float4* wr = (const float4*)(Wbase + (size_t)row * 512 + koff);
            const float4 w0 = wr[0], w1 = wr[1], w2 = wr[2], w3 = wr[3];
            float acc = w0.x * xr0.x + w0.y * xr0.y + w0.z * xr0.z + w0.w * xr0.w
                      + w1.x * xr1.x + w1.y * xr1.y + w1.z * xr1.z + w1.w * xr1.w
                      + w2.x * xr2.x + w2.y * xr2.y + w2.z * xr2.z + w2.w * xr2.w
                      + w3.x * xr3.x + w3.y * xr3.y + w3.z * xr3.z + w3.w * xr3.w;
            #pragma unroll
            for (int off = 32; off > 0; off >>= 1)
                acc += __shfl_xor(acc, off, 64);
            if (lane == 0) gates[row] = acc;
        }
        __syncthreads();

        if (tid < Hv) {
            const int cc = tid;
            const float gi = sigmf_(gates[0 * Hv + cc] + bias[0 * Hv + cc]);
            const float gf = sigmf_(gates[1 * Hv + cc] + bias[1 * Hv + cc]);
            const float gg = tanhf_(gates[2 * Hv + cc] + bias[2 * Hv + cc]);
            const float go = sigmf_(gates[3 * Hv + cc] + bias[3 * Hv + cc]);
            const float cn = gf * cst[cc] + gi * gg;
            const float hn = go * tanhf_(cn);
            const bool v = (t < len);
            const float hnew = v ? hn : xh[Dv + cc];
            cst[cc] = v ? cn : cst[cc];
            xh[Dv + cc] = hnew;
            out[((size_t)b * Tv + t) * (2 * Hv) + dir * Hv + cc] = hnew;
        }
    }
}

extern "C" void kernel_launch(void* const* d_in, const int* in_sizes, int n_in,
                              void* d_out, int out_size, void* d_ws, size_t ws_size,
                              hipStream_t stream) {
    (void)out_size;

    const void *xv, *len_p, *Wihf, *Whhf, *bihf, *bhhf, *Wihb, *Whhb, *bihb, *bhhb;
    if (n_in == 10 && in_sizes[9] == 8388608 && in_sizes[8] == 32) {
        // alphabetical pytree order fallback
        Whhb = d_in[0]; Whhf = d_in[1]; Wihb = d_in[2]; Wihf = d_in[3];
        bhhb = d_in[4]; bhhf = d_in[5]; bihb = d_in[6]; bihf = d_in[7];
        len_p = d_in[8]; xv = d_in[9];
    } else {
        // documented dict order
        xv = d_in[0]; len_p = d_in[1];
        Wihf = d_in[2]; Whhf = d_in[3]; bihf = d_in[4]; bhhf = d_in[5];
        Wihb = d_in[6]; Whhb = d_in[7]; bihb = d_in[8]; bhhb = d_in[9];
    }

    const float* xf  = (const float*)xv;
    const int*   lp  = (const int*)len_p;
    const float* wif = (const float*)Wihf;  const float* whf = (const float*)Whhf;
    const float* bif = (const float*)bihf;  const float* bhf = (const float*)bhhf;
    const float* wib = (const float*)Wihb;  const float* whb = (const float*)Whhb;
    const float* bib = (const float*)bihb;  const float* bhb = (const float*)bhhb;
    float* outp = (float*)d_out;
    unsigned int* cntp = (unsigned int*)d_ws;

    if (ws_size >= 2048) {
        void* args[12] = { &xf, &lp, &wif, &whf, &bif, &bhf,
                           &wib, &whb, &bib, &bhb, &outp, &cntp };
        hipError_t e = hipLaunchCooperativeKernel((const void*)bilstm_coop3,
                                                  dim3(256), dim3(512),
                                                  args, 0, stream);
        if (e == hipSuccess) return;
    }

    // fallback: R10 kernel
    bilstm_simple<<<dim3(64), dim3(1024), 0, stream>>>(
        xf, lp, wif, whf, bif, bhf, wib, whb, bib, bhb, outp);
}